// Round 5
// baseline (665.472 us; speedup 1.0000x reference)
//
#include <hip/hip_runtime.h>
#include <math.h>

#define PI_F 3.14159265358979323846f
// Wave-level LDS sync (k_col only): DS ops from one wave execute in order; waitcnt drains
// them, "memory" clobber stops compiler reordering. No s_barrier for wave-private data.
#define WSYNC() asm volatile("s_waitcnt lgkmcnt(0)" ::: "memory")

// ---------------- complex helpers ----------------
__device__ __forceinline__ float2 cmul(float2 a, float2 b) {      // a*b
    return make_float2(a.x * b.x - a.y * b.y, a.x * b.y + a.y * b.x);
}
__device__ __forceinline__ float2 cmulc(float2 a, float2 b) {     // a*conj(b)
    return make_float2(a.x * b.x + a.y * b.y, a.y * b.x - a.x * b.y);
}
__device__ __forceinline__ int bitrev8(int p) {                   // reverse 8 bits
    return (int)(__brev((unsigned int)p) >> 24);
}
__device__ __forceinline__ int br4(int z) { return ((z & 3) << 2) | (z >> 2); }  // swap 2 base-4 digits
// XOR bank-swizzle within a 256-point line (k_col LDS): logical elem e -> e ^ ((e>>4)&15).
// bank-pair(e) = (e&15) ^ (e>>4): minimal 4 lanes/bank-pair for BOTH stride-16 and
// consecutive-16 wave access patterns (and the 4-elem staging accesses).
__device__ __forceinline__ int SW(int i) { return i ^ ((i >> 4) & 15); }

// ---------------- radix-4 butterfly cores (twiddle-free) ----------------
__device__ __forceinline__ void bfly4_fwd(float2 a0, float2 a1, float2 a2, float2 a3,
                                          float2& o0, float2& o1, float2& o2, float2& o3) {
    float2 t0 = make_float2(a0.x + a2.x, a0.y + a2.y);
    float2 t1 = make_float2(a0.x - a2.x, a0.y - a2.y);
    float2 t2 = make_float2(a1.x + a3.x, a1.y + a3.y);
    float2 u  = make_float2(a1.x - a3.x, a1.y - a3.y);
    float2 t3 = make_float2(u.y, -u.x);                 // -i*u
    o0 = make_float2(t0.x + t2.x, t0.y + t2.y);
    o1 = make_float2(t1.x + t3.x, t1.y + t3.y);
    o2 = make_float2(t0.x - t2.x, t0.y - t2.y);
    o3 = make_float2(t1.x - t3.x, t1.y - t3.y);
}
__device__ __forceinline__ void bfly4_inv(float2 a0, float2 a1, float2 a2, float2 a3,
                                          float2& o0, float2& o1, float2& o2, float2& o3) {
    float2 t0 = make_float2(a0.x + a2.x, a0.y + a2.y);
    float2 t1 = make_float2(a0.x - a2.x, a0.y - a2.y);
    float2 t2 = make_float2(a1.x + a3.x, a1.y + a3.y);
    float2 u  = make_float2(a1.x - a3.x, a1.y - a3.y);
    float2 t3 = make_float2(-u.y, u.x);                 // +i*u
    o0 = make_float2(t0.x + t2.x, t0.y + t2.y);
    o1 = make_float2(t1.x + t3.x, t1.y + t3.y);
    o2 = make_float2(t0.x - t2.x, t0.y - t2.y);
    o3 = make_float2(t1.x - t3.x, t1.y - t3.y);
}

// ---------------- in-register 16-point FFT (radix-4 DIF x2). reg r <-> X[br4(r)] ----------------
#define W16_1 make_float2( 0.92387953f, -0.38268343f)
#define W16_2 make_float2( 0.70710678f, -0.70710678f)
#define W16_3 make_float2( 0.38268343f, -0.92387953f)
#define W16_4 make_float2( 0.0f,        -1.0f)
#define W16_6 make_float2(-0.70710678f, -0.70710678f)
#define W16_9 make_float2(-0.92387953f,  0.38268343f)

__device__ __forceinline__ void fft16_fwd(float2* v) {
    float2 o0, o1, o2, o3;
    bfly4_fwd(v[0], v[4], v[8],  v[12], o0, o1, o2, o3);
    v[0] = o0; v[4] = o1; v[8] = o2; v[12] = o3;
    bfly4_fwd(v[1], v[5], v[9],  v[13], o0, o1, o2, o3);
    v[1] = o0; v[5] = cmul(o1, W16_1); v[9]  = cmul(o2, W16_2); v[13] = cmul(o3, W16_3);
    bfly4_fwd(v[2], v[6], v[10], v[14], o0, o1, o2, o3);
    v[2] = o0; v[6] = cmul(o1, W16_2); v[10] = cmul(o2, W16_4); v[14] = cmul(o3, W16_6);
    bfly4_fwd(v[3], v[7], v[11], v[15], o0, o1, o2, o3);
    v[3] = o0; v[7] = cmul(o1, W16_3); v[11] = cmul(o2, W16_6); v[15] = cmul(o3, W16_9);
#pragma unroll
    for (int g = 0; g < 4; ++g) {
        bfly4_fwd(v[4*g], v[4*g+1], v[4*g+2], v[4*g+3], o0, o1, o2, o3);
        v[4*g] = o0; v[4*g+1] = o1; v[4*g+2] = o2; v[4*g+3] = o3;
    }
}
__device__ __forceinline__ void fft16_inv(float2* v) {            // consumes br4-ordered regs
    float2 o0, o1, o2, o3;
#pragma unroll
    for (int g = 0; g < 4; ++g) {
        bfly4_inv(v[4*g], v[4*g+1], v[4*g+2], v[4*g+3], o0, o1, o2, o3);
        v[4*g] = o0; v[4*g+1] = o1; v[4*g+2] = o2; v[4*g+3] = o3;
    }
    bfly4_inv(v[0], v[4], v[8], v[12], o0, o1, o2, o3);
    v[0] = o0; v[4] = o1; v[8] = o2; v[12] = o3;
    bfly4_inv(v[1], cmulc(v[5], W16_1), cmulc(v[9],  W16_2), cmulc(v[13], W16_3), o0, o1, o2, o3);
    v[1] = o0; v[5] = o1; v[9] = o2; v[13] = o3;
    bfly4_inv(v[2], cmulc(v[6], W16_2), cmulc(v[10], W16_4), cmulc(v[14], W16_6), o0, o1, o2, o3);
    v[2] = o0; v[6] = o1; v[10] = o2; v[14] = o3;
    bfly4_inv(v[3], cmulc(v[7], W16_3), cmulc(v[11], W16_6), cmulc(v[15], W16_9), o0, o1, o2, o3);
    v[3] = o0; v[7] = o1; v[11] = o2; v[15] = o3;
}

// ---------------- register FFT along W: radix-2 shfl_xor stages, zero LDS ----------------
// Layout: lane L holds elements 4L..4L+3 of a 256-line (2 lines a[],b[] per wave).
// Forward DIF, stages h=128..4 cross-lane (mask = h/4), h=2,1 lane-local.
// Output position p holds frequency bitrev8(p). Sum-lanes get exact (1,0) twiddle.
// LUT variants take 4 precomputed twiddles (W-angle = dm*step*((lane&(MB-1)) + 0.25*d)).
template<int MB>
__device__ __forceinline__ void xs_fwd_l(float2* a, float2* b, int lane, const float2* tw) {
    float s = (lane & MB) ? -1.0f : 1.0f;
#pragma unroll
    for (int d = 0; d < 4; ++d) {
        float tax = __shfl_xor(a[d].x, MB), tay = __shfl_xor(a[d].y, MB);
        float tbx = __shfl_xor(b[d].x, MB), tby = __shfl_xor(b[d].y, MB);
        float2 ra = make_float2(tax + s * a[d].x, tay + s * a[d].y);
        float2 rb = make_float2(tbx + s * b[d].x, tby + s * b[d].y);
        a[d] = cmul(ra, tw[d]);
        b[d] = cmul(rb, tw[d]);
    }
}
template<int MB>
__device__ __forceinline__ void xs_inv_l(float2* a, float2* b, int lane, const float2* tw) {
    float s = (lane & MB) ? -1.0f : 1.0f;
#pragma unroll
    for (int d = 0; d < 4; ++d) {
        float2 pa = cmulc(a[d], tw[d]);                 // conj of fwd twiddle
        float2 pb = cmulc(b[d], tw[d]);
        float tax = __shfl_xor(pa.x, MB), tay = __shfl_xor(pa.y, MB);
        float tbx = __shfl_xor(pb.x, MB), tby = __shfl_xor(pb.y, MB);
        a[d] = make_float2(tax + s * pa.x, tay + s * pa.y);
        b[d] = make_float2(tbx + s * pb.x, tby + s * pb.y);
    }
}
// sincos fallbacks (no workspace) — identical to the proven round-3 path
template<int MB>
__device__ __forceinline__ void xs_fwd(float2* a, float2* b, int lane,
                                       float step, float cC, float sC) {
    float dm = (lane & MB) ? 1.0f : 0.0f;
    float s  = 1.0f - 2.0f * dm;
    float ang = step * dm * (float)(lane & (MB - 1));
    float sn, cs; __sincosf(ang, &sn, &cs);
    float2 tw = make_float2(cs, sn);
    float2 Cm = make_float2(1.0f + dm * (cC - 1.0f), dm * sC);
#pragma unroll
    for (int d = 0; d < 4; ++d) {
        float tax = __shfl_xor(a[d].x, MB), tay = __shfl_xor(a[d].y, MB);
        float tbx = __shfl_xor(b[d].x, MB), tby = __shfl_xor(b[d].y, MB);
        float2 ra = make_float2(tax + s * a[d].x, tay + s * a[d].y);
        float2 rb = make_float2(tbx + s * b[d].x, tby + s * b[d].y);
        a[d] = cmul(ra, tw);
        b[d] = cmul(rb, tw);
        tw = cmul(tw, Cm);
    }
}
template<int MB>
__device__ __forceinline__ void xs_inv(float2* a, float2* b, int lane,
                                       float step, float cC, float sC) {
    float dm = (lane & MB) ? 1.0f : 0.0f;
    float s  = 1.0f - 2.0f * dm;
    float ang = step * dm * (float)(lane & (MB - 1));
    float sn, cs; __sincosf(ang, &sn, &cs);
    float2 tw = make_float2(cs, sn);
    float2 Cm = make_float2(1.0f + dm * (cC - 1.0f), dm * sC);
#pragma unroll
    for (int d = 0; d < 4; ++d) {
        float2 pa = cmul(a[d], tw);
        float2 pb = cmul(b[d], tw);
        float tax = __shfl_xor(pa.x, MB), tay = __shfl_xor(pa.y, MB);
        float tbx = __shfl_xor(pb.x, MB), tby = __shfl_xor(pb.y, MB);
        a[d] = make_float2(tax + s * pa.x, tay + s * pa.y);
        b[d] = make_float2(tbx + s * pb.x, tby + s * pb.y);
        tw = cmul(tw, Cm);
    }
}
// Lane-local tail: fwd h=2 then h=1
__device__ __forceinline__ void local_fwd(float2* v) {
    float2 u0 = make_float2(v[0].x + v[2].x, v[0].y + v[2].y);
    float2 u2 = make_float2(v[0].x - v[2].x, v[0].y - v[2].y);
    float2 u1 = make_float2(v[1].x + v[3].x, v[1].y + v[3].y);
    float2 w  = make_float2(v[1].x - v[3].x, v[1].y - v[3].y);
    float2 u3 = make_float2(w.y, -w.x);                 // -i*w
    v[0] = make_float2(u0.x + u1.x, u0.y + u1.y);
    v[1] = make_float2(u0.x - u1.x, u0.y - u1.y);
    v[2] = make_float2(u2.x + u3.x, u2.y + u3.y);
    v[3] = make_float2(u2.x - u3.x, u2.y - u3.y);
}
__device__ __forceinline__ void local_inv(float2* v) {
    float2 u0 = make_float2(v[0].x + v[1].x, v[0].y + v[1].y);
    float2 u1 = make_float2(v[0].x - v[1].x, v[0].y - v[1].y);
    float2 u2 = make_float2(v[2].x + v[3].x, v[2].y + v[3].y);
    float2 u3 = make_float2(v[2].x - v[3].x, v[2].y - v[3].y);
    float2 w  = make_float2(-u3.y, u3.x);               // +i*u3
    v[0] = make_float2(u0.x + u2.x, u0.y + u2.y);
    v[2] = make_float2(u0.x - u2.x, u0.y - u2.y);
    v[1] = make_float2(u1.x + w.x, u1.y + w.y);
    v[3] = make_float2(u1.x - w.x, u1.y - w.y);
}

// gain of the (fftshift-space) reference at centered freq (fy, fx)
__device__ __forceinline__ float gain1(float fy, float fx, const float* sw) {
    float r2 = fy * fy + fx * fx;
    float theta = atan2f(fy, fx) + PI_F;
    int idx = ((int)floorf(theta * (4.0f / PI_F))) & 7;
    float wv = sw[idx];
    return (r2 > 1474.56f) ? wv : 1.0f;                 // r > 0.3*128, r^2 integer
}

// ---------------- workspace layout (floats): ----------------
//   [0, 65536)           gain lut2[w][h]   (W order = bitrev8; H order: see below)
//   [65536, 65536+3072)  row twiddles: float2 rtw[st][lane][d], st=0..5 (MB=32>>st)
//   [68608, 68608+512)   k_col twiddles: float2 twc[j*16+r] = W256^{j*br4(r)}
#define WS_RTW 65536
#define WS_TWC 68608
#define WS_FLOATS 69120

__global__ __launch_bounds__(256) void k_luts(const float* __restrict__ wts, float* __restrict__ ws) {
    __shared__ float sw[8];
    int h = threadIdx.x, w = blockIdx.x;
    if (h < 8) sw[h] = wts[h];
    __syncthreads();
    // gain LUT storage index h = 16*j + r (j = k_col lane digit, r = register).
    // Phase-B frequency at (lane j, reg r): kh = br4(j) + 16*br4(r)   [k1 = br4(j), k2 = br4(r)]
    int kw = bitrev8(w);
    int kh = br4(h >> 4) + (br4(h & 15) << 4);
    float fx  = (kw < 128) ? (float)kw : (float)(kw - 256);
    float fx2 = (kw == 128) ? -128.0f : -fx;
    float fy  = (kh < 128) ? (float)kh : (float)(kh - 256);
    float fy2 = (kh == 128) ? -128.0f : -fy;
    float g1 = gain1(fy, fx, sw);
    float g2 = gain1(fy2, fx2, sw);                     // symmetrize -> real filter
    ws[w * 256 + h] = (1.0f + 0.5f * (g1 + g2)) * (1.0f / 65536.0f);
    if (w == 0) {                                       // row twiddle table: 1536 float2
        float2* rtw = (float2*)(ws + WS_RTW);
        int lane = h >> 2, d = h & 3;
#pragma unroll
        for (int st = 0; st < 6; ++st) {
            int MB = 32 >> st;
            float step = -PI_F / (float)MB;
            float dm = (lane & MB) ? 1.0f : 0.0f;
            float th = dm * step * ((float)(lane & (MB - 1)) + 0.25f * (float)d);
            float sn, cs; sincosf(th, &sn, &cs);
            rtw[st * 256 + h] = make_float2(cs, sn);
        }
    }
    if (w == 1) {                                       // k_col twiddle table: 256 float2
        float2* twc = (float2*)(ws + WS_TWC);
        int j = h >> 4, r = h & 15;
        float th = -(2.0f * PI_F / 256.0f) * (float)(j * br4(r));
        float sn, cs; sincosf(th, &sn, &cs);
        twc[h] = make_float2(cs, sn);
    }
}

// ---------------- Pass 1: forward FFT along W, fully in registers. Wave owns 2 rows. ----------------
template<bool TW>
__global__ __launch_bounds__(256) void k_row_fwd(const float* __restrict__ x, float* __restrict__ out,
                                                 const float* __restrict__ ws) {
    int t = threadIdx.x, wv = t >> 6, lane = t & 63;
    int gr = blockIdx.x * 8 + wv * 2;                   // global row id (pair-aligned, same image)
    int q = gr >> 8, h = gr & 255;
    int plane = ((q >> 7) << 8) + ((q & 127) << 1);
    size_t rA = ((size_t)plane << 16) + ((size_t)h << 8);
    size_t rB = rA + 65536;
    int w4 = lane * 4;
    float4 re0 = *(const float4*)(x + rA + w4);
    float4 im0 = *(const float4*)(x + rB + w4);
    float4 re1 = *(const float4*)(x + rA + 256 + w4);
    float4 im1 = *(const float4*)(x + rB + 256 + w4);
    float2 a[4], b[4];
    a[0] = make_float2(re0.x, im0.x); a[1] = make_float2(re0.y, im0.y);
    a[2] = make_float2(re0.z, im0.z); a[3] = make_float2(re0.w, im0.w);
    b[0] = make_float2(re1.x, im1.x); b[1] = make_float2(re1.y, im1.y);
    b[2] = make_float2(re1.z, im1.z); b[3] = make_float2(re1.w, im1.w);
    if (TW) {
        const float4* rtw = (const float4*)(ws + WS_RTW);
        float2 tw[6][4];
#pragma unroll
        for (int s = 0; s < 6; ++s) {
            float4 lo = rtw[(s * 64 + lane) * 2];
            float4 hi = rtw[(s * 64 + lane) * 2 + 1];
            tw[s][0] = make_float2(lo.x, lo.y); tw[s][1] = make_float2(lo.z, lo.w);
            tw[s][2] = make_float2(hi.x, hi.y); tw[s][3] = make_float2(hi.z, hi.w);
        }
        xs_fwd_l<32>(a, b, lane, tw[0]);
        xs_fwd_l<16>(a, b, lane, tw[1]);
        xs_fwd_l< 8>(a, b, lane, tw[2]);
        xs_fwd_l< 4>(a, b, lane, tw[3]);
        xs_fwd_l< 2>(a, b, lane, tw[4]);
        xs_fwd_l< 1>(a, b, lane, tw[5]);
    } else {
        xs_fwd<32>(a, b, lane, -0.09817477f, 0.99969882f, -0.02454123f);
        xs_fwd<16>(a, b, lane, -0.19634954f, 0.99879546f, -0.04906767f);
        xs_fwd< 8>(a, b, lane, -0.39269908f, 0.99518473f, -0.09801714f);
        xs_fwd< 4>(a, b, lane, -0.78539816f, 0.98078528f, -0.19509032f);
        xs_fwd< 2>(a, b, lane, -1.57079633f, 0.92387953f, -0.38268343f);
        xs_fwd< 1>(a, b, lane, -3.14159265f, 0.70710678f, -0.70710678f);
    }
    local_fwd(a); local_fwd(b);
    *(float4*)(out + rA + w4)       = make_float4(a[0].x, a[1].x, a[2].x, a[3].x);
    *(float4*)(out + rB + w4)       = make_float4(a[0].y, a[1].y, a[2].y, a[3].y);
    *(float4*)(out + rA + 256 + w4) = make_float4(b[0].x, b[1].x, b[2].x, b[3].x);
    *(float4*)(out + rB + 256 + w4) = make_float4(b[0].y, b[1].y, b[2].y, b[3].y);
}

// ---------------- Pass 2: col FFT + gain + col IFFT. Radix-16, one column per lane. ----------------
// Lane (col = wv*4 + (lane&3), j = lane>>2). Phases (WSYNC = wave-level, cross-lane within wave):
//  A: read slots {j+16m} -> fft16 over m -> *W256^{j*br4(r)} -> write {j+16r}
//  B: read slots {16j+i} -> fft16 over n1 -> gain (kh = br4(j)+16*br4(r)) -> ifft16 -> write
//  C: read slots {j+16r} -> *conj twiddle -> ifft16 over k1 -> write {j+16m}
template<bool USE_LUT>
__global__ __launch_bounds__(256) void k_col(float* __restrict__ data,
                                             const float* __restrict__ ws,
                                             const float* __restrict__ wts) {
    __shared__ float2 tile[16][256];                    // 32 KiB exactly
    int t = threadIdx.x;
    int q = blockIdx.x >> 4, wt = blockIdx.x & 15, w0 = wt * 16;
    int plane = ((q >> 7) << 8) + ((q & 127) << 1);
    size_t baseA = ((size_t)plane << 16) + (size_t)w0;
    size_t baseB = baseA + 65536;
    int c0 = (t & 3) * 4, h0 = (t >> 2) * 4;
    int wv = t >> 6, lane = t & 63;
    int col = wv * 4 + (lane & 3);
    int j = lane >> 2;                                  // 0..15

    // -------- twiddles + gains into registers (issued early; latency hides under staging) --------
    float2 twc[16];
    float  g_[16];
    if (USE_LUT) {
        const float4* tp = (const float4*)(ws + WS_TWC) + j * 8;
        const float4* gp = (const float4*)(ws + (size_t)(w0 + col) * 256 + (j << 4));
#pragma unroll
        for (int k = 0; k < 8; ++k) {
            float4 c4 = tp[k];
            twc[2 * k]     = make_float2(c4.x, c4.y);
            twc[2 * k + 1] = make_float2(c4.z, c4.w);
        }
#pragma unroll
        for (int k = 0; k < 4; ++k) {
            float4 g4 = gp[k];
            g_[4 * k] = g4.x; g_[4 * k + 1] = g4.y; g_[4 * k + 2] = g4.z; g_[4 * k + 3] = g4.w;
        }
    } else {
        __shared__ float swf[8];
        if (t < 8) swf[t] = wts[t];
        __syncthreads();
        int kw = bitrev8(w0 + col);
        float fx  = (kw < 128) ? (float)kw : (float)(kw - 256);
        float fx2 = (kw == 128) ? -128.0f : -fx;
#pragma unroll
        for (int r = 0; r < 16; ++r) {
            float sn, cs;
            __sincosf(-(2.0f * PI_F / 256.0f) * (float)(j * br4(r)), &sn, &cs);
            twc[r] = make_float2(cs, sn);
            int kh = br4(j) + (br4(r) << 4);            // k1 = br4(j), k2 = br4(r)
            float fy  = (kh < 128) ? (float)kh : (float)(kh - 256);
            float fy2 = (kh == 128) ? -128.0f : -fy;
            float g1v = gain1(fy, fx, swf);
            float g2v = gain1(fy2, fx2, swf);
            g_[r] = (1.0f + 0.5f * (g1v + g2v)) * (1.0f / 65536.0f);
        }
    }

    // -------- staging in: thread -> cols c0..c0+3, rows h0..h0+3 (b64 LDS writes, swizzled) --------
    {
        float4 reR[4], imR[4];
#pragma unroll
        for (int r = 0; r < 4; ++r) {
            reR[r] = *(const float4*)(data + baseA + (size_t)(h0 + r) * 256 + c0);
            imR[r] = *(const float4*)(data + baseB + (size_t)(h0 + r) * 256 + c0);
        }
#pragma unroll
        for (int r = 0; r < 4; ++r) {
            int p = SW(h0 + r);
#pragma unroll
            for (int k = 0; k < 4; ++k)
                tile[c0 + k][p] = make_float2((&reR[r].x)[k], (&imR[r].x)[k]);
        }
    }
    __syncthreads();

    float2* L = tile[col];
    float2 v[16];
    // -------- Phase A: DFT16 over stride-16 digit + twiddle (lane-own slots, in-place) --------
#pragma unroll
    for (int m = 0; m < 16; ++m) v[m] = L[(m << 4) + (j ^ m)];
    fft16_fwd(v);
#pragma unroll
    for (int r = 0; r < 16; ++r) v[r] = cmul(v[r], twc[r]);
#pragma unroll
    for (int r = 0; r < 16; ++r) L[(r << 4) + (j ^ r)] = v[r];
    WSYNC();
    // -------- Phase B: DFT16 over low digit + gain + inverse --------
#pragma unroll
    for (int i = 0; i < 16; ++i) v[i] = L[(j << 4) + (i ^ j)];
    fft16_fwd(v);
#pragma unroll
    for (int r = 0; r < 16; ++r) { v[r].x *= g_[r]; v[r].y *= g_[r]; }
    fft16_inv(v);
#pragma unroll
    for (int n = 0; n < 16; ++n) L[(j << 4) + (n ^ j)] = v[n];
    WSYNC();
    // -------- Phase C: conj twiddle + inverse DFT16 over stride-16 digit --------
#pragma unroll
    for (int r = 0; r < 16; ++r) v[r] = cmulc(L[(r << 4) + (j ^ r)], twc[r]);
    fft16_inv(v);
#pragma unroll
    for (int m = 0; m < 16; ++m) L[(m << 4) + (j ^ m)] = v[m];
    __syncthreads();

    // -------- staging out (mirror of staging in) --------
    {
#pragma unroll
        for (int r = 0; r < 4; ++r) {
            int p = SW(h0 + r);
            float2 v0 = tile[c0 + 0][p], v1 = tile[c0 + 1][p];
            float2 v2 = tile[c0 + 2][p], v3 = tile[c0 + 3][p];
            *(float4*)(data + baseA + (size_t)(h0 + r) * 256 + c0) = make_float4(v0.x, v1.x, v2.x, v3.x);
            *(float4*)(data + baseB + (size_t)(h0 + r) * 256 + c0) = make_float4(v0.y, v1.y, v2.y, v3.y);
        }
    }
}

// ---------------- Pass 3: inverse FFT along W, fully in registers. Wave owns 2 rows. ----------------
template<bool TW>
__global__ __launch_bounds__(256) void k_row_inv(float* __restrict__ data, const float* __restrict__ ws) {
    int t = threadIdx.x, wv = t >> 6, lane = t & 63;
    int gr = blockIdx.x * 8 + wv * 2;
    int q = gr >> 8, h = gr & 255;
    int plane = ((q >> 7) << 8) + ((q & 127) << 1);
    size_t rA = ((size_t)plane << 16) + ((size_t)h << 8);
    size_t rB = rA + 65536;
    int w4 = lane * 4;
    float4 re0 = *(const float4*)(data + rA + w4);
    float4 im0 = *(const float4*)(data + rB + w4);
    float4 re1 = *(const float4*)(data + rA + 256 + w4);
    float4 im1 = *(const float4*)(data + rB + 256 + w4);
    float2 a[4], b[4];
    a[0] = make_float2(re0.x, im0.x); a[1] = make_float2(re0.y, im0.y);
    a[2] = make_float2(re0.z, im0.z); a[3] = make_float2(re0.w, im0.w);
    b[0] = make_float2(re1.x, im1.x); b[1] = make_float2(re1.y, im1.y);
    b[2] = make_float2(re1.z, im1.z); b[3] = make_float2(re1.w, im1.w);
    local_inv(a); local_inv(b);
    if (TW) {
        const float4* rtw = (const float4*)(ws + WS_RTW);
        float2 tw[6][4];
#pragma unroll
        for (int s = 0; s < 6; ++s) {
            float4 lo = rtw[(s * 64 + lane) * 2];
            float4 hi = rtw[(s * 64 + lane) * 2 + 1];
            tw[s][0] = make_float2(lo.x, lo.y); tw[s][1] = make_float2(lo.z, lo.w);
            tw[s][2] = make_float2(hi.x, hi.y); tw[s][3] = make_float2(hi.z, hi.w);
        }
        xs_inv_l< 1>(a, b, lane, tw[5]);
        xs_inv_l< 2>(a, b, lane, tw[4]);
        xs_inv_l< 4>(a, b, lane, tw[3]);
        xs_inv_l< 8>(a, b, lane, tw[2]);
        xs_inv_l<16>(a, b, lane, tw[1]);
        xs_inv_l<32>(a, b, lane, tw[0]);
    } else {
        xs_inv< 1>(a, b, lane,  3.14159265f, 0.70710678f,  0.70710678f);
        xs_inv< 2>(a, b, lane,  1.57079633f, 0.92387953f,  0.38268343f);
        xs_inv< 4>(a, b, lane,  0.78539816f, 0.98078528f,  0.19509032f);
        xs_inv< 8>(a, b, lane,  0.39269908f, 0.99518473f,  0.09801714f);
        xs_inv<16>(a, b, lane,  0.19634954f, 0.99879546f,  0.04906767f);
        xs_inv<32>(a, b, lane,  0.09817477f, 0.99969882f,  0.02454123f);
    }
    *(float4*)(data + rA + w4)       = make_float4(a[0].x, a[1].x, a[2].x, a[3].x);   // re -> ch 2c
    *(float4*)(data + rB + w4)       = make_float4(a[0].y, a[1].y, a[2].y, a[3].y);   // im -> ch 2c+1
    *(float4*)(data + rA + 256 + w4) = make_float4(b[0].x, b[1].x, b[2].x, b[3].x);
    *(float4*)(data + rB + 256 + w4) = make_float4(b[0].y, b[1].y, b[2].y, b[3].y);
}

extern "C" void kernel_launch(void* const* d_in, const int* in_sizes, int n_in,
                              void* d_out, int out_size, void* d_ws, size_t ws_size,
                              hipStream_t stream) {
    const float* x   = (const float*)d_in[0];
    const float* wts = (const float*)d_in[1];
    float* out = (float*)d_out;
    float* wsf = (float*)d_ws;
    (void)in_sizes; (void)n_in; (void)out_size;
    bool use_lut = (ws_size >= (size_t)WS_FLOATS * sizeof(float)) && (d_ws != nullptr);
    // 512 image-pairs (B=4, C=256 paired), H=W=256; 131072 rows total, 8 per block
    if (use_lut) {
        k_luts<<<256, 256, 0, stream>>>(wts, wsf);
        k_row_fwd<true><<<16384, 256, 0, stream>>>(x, out, wsf);
        k_col<true><<<8192, 256, 0, stream>>>(out, wsf, wts);
        k_row_inv<true><<<16384, 256, 0, stream>>>(out, wsf);
    } else {
        k_row_fwd<false><<<16384, 256, 0, stream>>>(x, out, nullptr);
        k_col<false><<<8192, 256, 0, stream>>>(out, nullptr, wts);
        k_row_inv<false><<<16384, 256, 0, stream>>>(out, nullptr);
    }
}